// Round 3
// baseline (24.444 us; speedup 1.0000x reference)
//
#include <hip/hip_runtime.h>
#include <math.h>

// ForwardKinematics: B graphs x 24 joints, fixed tree (compile-time).
// Monotone DFS order: 0..23 with resets J5<-R0, J9<-R0, J14<-R11, J18<-R11, J22<-R12.
// Block = 64 threads = 1 wave = 64 graphs. ALL inputs preloaded into registers
// at kernel start (72 coalesced loads in flight -> HBM saturated immediately;
// only 1 wave/SIMD exists so ILP is the only latency hiding). Chunks of 6
// joints staged reg->LDS transposed [feature][graph], stride 65 (conflict-free
// compute reads). Output staged transposed, flushed in two halves so half the
// stores overlap compute.

#define GPB 64
#define PAD 65

__device__ __forceinline__ void rot6d(float a0, float a1, float a2,
                                      float a3, float a4, float a5,
                                      float T[9]) {
    float n1 = sqrtf(a0*a0 + a1*a1 + a2*a2) + 1e-12f;
    float i1 = 1.0f / n1;
    float b1x = a0*i1, b1y = a1*i1, b1z = a2*i1;
    float d = b1x*a3 + b1y*a4 + b1z*a5;
    float ax = a3 - d*b1x, ay = a4 - d*b1y, az = a5 - d*b1z;
    float n2 = sqrtf(ax*ax + ay*ay + az*az) + 1e-12f;
    float i2 = 1.0f / n2;
    float b2x = ax*i2, b2y = ay*i2, b2z = az*i2;
    T[0] = b1x; T[1] = b1y; T[2] = b1z;
    T[3] = b2x; T[4] = b2y; T[5] = b2z;
    T[6] = b1y*b2z - b1z*b2y;
    T[7] = b1z*b2x - b1x*b2z;
    T[8] = b1x*b2y - b1y*b2x;
}

// Stage one 6-joint chunk from registers into transposed LDS.
__device__ __forceinline__ void write_lds(float* xs, float* os_, int t,
                                          const float4 xr[9], const float2 orr[9]) {
#pragma unroll
    for (int k = 0; k < 9; ++k) {
        int i = k * GPB + t;
        int g = i / 9, e = i - g * 9;
        xs[(4*e+0)*PAD + g] = xr[k].x;
        xs[(4*e+1)*PAD + g] = xr[k].y;
        xs[(4*e+2)*PAD + g] = xr[k].z;
        xs[(4*e+3)*PAD + g] = xr[k].w;
        os_[(2*e+0)*PAD + g] = orr[k].x;
        os_[(2*e+1)*PAD + g] = orr[k].y;
    }
}

// One chain step: joint J (jl = J%6 within the staged chunk).
template<int J>
__device__ __forceinline__ void joint_step(const float* xs, const float* os_,
                                           float* outs, int t,
                                           float R[9], float Pc[3]) {
    constexpr int jl = J % 6;
    float a0 = xs[(jl*6+0)*PAD + t];
    float a1 = xs[(jl*6+1)*PAD + t];
    float a2 = xs[(jl*6+2)*PAD + t];
    float a3 = xs[(jl*6+3)*PAD + t];
    float a4 = xs[(jl*6+4)*PAD + t];
    float a5 = xs[(jl*6+5)*PAD + t];
    float T[9];
    rot6d(a0, a1, a2, a3, a4, a5, T);
    float o0 = os_[(jl*3+0)*PAD + t];
    float o1 = os_[(jl*3+1)*PAD + t];
    float o2 = os_[(jl*3+2)*PAD + t];
    float p0 = R[0]*o0 + R[1]*o1 + R[2]*o2 + Pc[0];
    float p1 = R[3]*o0 + R[4]*o1 + R[5]*o2 + Pc[1];
    float p2 = R[6]*o0 + R[7]*o1 + R[8]*o2 + Pc[2];
    float Rn[9];
#pragma unroll
    for (int i = 0; i < 3; ++i)
#pragma unroll
        for (int k = 0; k < 3; ++k)
            Rn[i*3+k] = R[i*3+0]*T[0+k] + R[i*3+1]*T[3+k] + R[i*3+2]*T[6+k];
#pragma unroll
    for (int i = 0; i < 9; ++i) R[i] = Rn[i];
    Pc[0] = p0; Pc[1] = p1; Pc[2] = p2;
    outs[(J*3+0)*PAD + t] = p0;
    outs[(J*3+1)*PAD + t] = p1;
    outs[(J*3+2)*PAD + t] = p2;
}

// Flush half H (joints 12H..12H+11 = outs rows 36H..36H+35) coalesced.
template<int H>
__device__ __forceinline__ void flush_half(const float* outs, float4* out4,
                                           long outb4, int t) {
#pragma unroll
    for (int k = 0; k < 9; ++k) {
        int i = k * GPB + t;
        int g = i / 9, e = i - g * 9;
        float4 v;
        v.x = outs[(36*H + 4*e + 0)*PAD + g];
        v.y = outs[(36*H + 4*e + 1)*PAD + g];
        v.z = outs[(36*H + 4*e + 2)*PAD + g];
        v.w = outs[(36*H + 4*e + 3)*PAD + g];
        out4[outb4 + (long)g*18 + 9*H + e] = v;
    }
}

__global__ __launch_bounds__(GPB, 1) void fk_kernel(const float* __restrict__ x,
                                                    const float* __restrict__ off,
                                                    float* __restrict__ out, int B) {
    __shared__ float xs[36 * PAD];
    __shared__ float os_[18 * PAD];
    __shared__ float outs[72 * PAD];
    int t = threadIdx.x;
    long gb0 = (long)blockIdx.x * GPB;
    const float4* x4 = (const float4*)x;
    const float2* o2g = (const float2*)off;
    long xb4 = gb0 * 36;
    long ob2 = gb0 * 36;

    // ---- preload EVERYTHING into registers (72 loads in flight) ----
    float4 xr[4][9];
    float2 orr[4][9];
#pragma unroll
    for (int c = 0; c < 4; ++c) {
#pragma unroll
        for (int k = 0; k < 9; ++k) {
            int i = k * GPB + t;
            int g = i / 9, e = i - g * 9;
            xr[c][k] = x4[xb4 + (long)g * 36 + c * 9 + e];
        }
#pragma unroll
        for (int k = 0; k < 9; ++k) {
            int i = k * GPB + t;
            int g = i / 9, e = i - g * 9;
            orr[c][k] = o2g[ob2 + (long)g * 36 + c * 9 + e];
        }
    }

    float R[9], Pc[3], R0[9], R11[9], P11[3], R12[9], P12[3];
    float4* out4 = (float4*)out;
    long outb4 = gb0 * 18;

    // ---- chunk 0: joints 0..5 ----
    write_lds(xs, os_, t, xr[0], orr[0]);
    __syncthreads();
    {   // J0 root: pos=0, R=T0
        float a0 = xs[0*PAD+t], a1 = xs[1*PAD+t], a2 = xs[2*PAD+t];
        float a3 = xs[3*PAD+t], a4 = xs[4*PAD+t], a5 = xs[5*PAD+t];
        rot6d(a0, a1, a2, a3, a4, a5, R);
        Pc[0] = Pc[1] = Pc[2] = 0.0f;
        outs[0*PAD+t] = 0.0f; outs[1*PAD+t] = 0.0f; outs[2*PAD+t] = 0.0f;
#pragma unroll
        for (int i = 0; i < 9; ++i) R0[i] = R[i];
    }
    joint_step<1>(xs, os_, outs, t, R, Pc);
    joint_step<2>(xs, os_, outs, t, R, Pc);
    joint_step<3>(xs, os_, outs, t, R, Pc);
    joint_step<4>(xs, os_, outs, t, R, Pc);
#pragma unroll
    for (int i = 0; i < 9; ++i) R[i] = R0[i];
    Pc[0] = Pc[1] = Pc[2] = 0.0f;
    joint_step<5>(xs, os_, outs, t, R, Pc);
    __syncthreads();

    // ---- chunk 1: joints 6..11 ----
    write_lds(xs, os_, t, xr[1], orr[1]);
    __syncthreads();
    joint_step<6>(xs, os_, outs, t, R, Pc);
    joint_step<7>(xs, os_, outs, t, R, Pc);
    joint_step<8>(xs, os_, outs, t, R, Pc);
#pragma unroll
    for (int i = 0; i < 9; ++i) R[i] = R0[i];
    Pc[0] = Pc[1] = Pc[2] = 0.0f;
    joint_step<9>(xs, os_, outs, t, R, Pc);
    joint_step<10>(xs, os_, outs, t, R, Pc);
    joint_step<11>(xs, os_, outs, t, R, Pc);
#pragma unroll
    for (int i = 0; i < 9; ++i) R11[i] = R[i];
    P11[0] = Pc[0]; P11[1] = Pc[1]; P11[2] = Pc[2];
    // joints 0..11 complete -> flush first half (overlaps later compute)
    flush_half<0>(outs, out4, outb4, t);
    __syncthreads();

    // ---- chunk 2: joints 12..17 ----
    write_lds(xs, os_, t, xr[2], orr[2]);
    __syncthreads();
    joint_step<12>(xs, os_, outs, t, R, Pc);
#pragma unroll
    for (int i = 0; i < 9; ++i) R12[i] = R[i];
    P12[0] = Pc[0]; P12[1] = Pc[1]; P12[2] = Pc[2];
    joint_step<13>(xs, os_, outs, t, R, Pc);
#pragma unroll
    for (int i = 0; i < 9; ++i) R[i] = R11[i];
    Pc[0] = P11[0]; Pc[1] = P11[1]; Pc[2] = P11[2];
    joint_step<14>(xs, os_, outs, t, R, Pc);
    joint_step<15>(xs, os_, outs, t, R, Pc);
    joint_step<16>(xs, os_, outs, t, R, Pc);
    joint_step<17>(xs, os_, outs, t, R, Pc);
    __syncthreads();

    // ---- chunk 3: joints 18..23 ----
    write_lds(xs, os_, t, xr[3], orr[3]);
    __syncthreads();
#pragma unroll
    for (int i = 0; i < 9; ++i) R[i] = R11[i];
    Pc[0] = P11[0]; Pc[1] = P11[1]; Pc[2] = P11[2];
    joint_step<18>(xs, os_, outs, t, R, Pc);
    joint_step<19>(xs, os_, outs, t, R, Pc);
    joint_step<20>(xs, os_, outs, t, R, Pc);
    joint_step<21>(xs, os_, outs, t, R, Pc);
#pragma unroll
    for (int i = 0; i < 9; ++i) R[i] = R12[i];
    Pc[0] = P12[0]; Pc[1] = P12[1]; Pc[2] = P12[2];
    joint_step<22>(xs, os_, outs, t, R, Pc);
    joint_step<23>(xs, os_, outs, t, R, Pc);
    // joints 12..23 complete -> flush second half (same-wave ds ordering)
    flush_half<1>(outs, out4, outb4, t);
}

// Fallback for B not divisible by GPB — not expected here.
__global__ __launch_bounds__(256) void fk_tail(const float* __restrict__ x,
                                               const float* __restrict__ off,
                                               float* __restrict__ out,
                                               int b0, int B) {
    int b = b0 + blockIdx.x * blockDim.x + threadIdx.x;
    if (b >= B) return;
    const float* xb = x + (size_t)b * 144;
    const float* ob = off + (size_t)b * 72;
    float* P = out + (size_t)b * 72;
    float R[9], Pc[3], R0[9], R11[9], P11[3], R12[9], P12[3];
    {
        rot6d(xb[0], xb[1], xb[2], xb[3], xb[4], xb[5], R);
        Pc[0] = Pc[1] = Pc[2] = 0.0f;
        P[0] = P[1] = P[2] = 0.0f;
        for (int i = 0; i < 9; ++i) R0[i] = R[i];
    }
    for (int j = 1; j < 24; ++j) {
        float Rp[9], Pp[3];
        if (j==1||j==5||j==9) { for (int i=0;i<9;++i) Rp[i]=R0[i]; Pp[0]=Pp[1]=Pp[2]=0.f; }
        else if (j==14||j==18) { for (int i=0;i<9;++i) Rp[i]=R11[i]; Pp[0]=P11[0];Pp[1]=P11[1];Pp[2]=P11[2]; }
        else if (j==22)   { for (int i=0;i<9;++i) Rp[i]=R12[i]; Pp[0]=P12[0];Pp[1]=P12[1];Pp[2]=P12[2]; }
        else              { for (int i=0;i<9;++i) Rp[i]=R[i];   Pp[0]=Pc[0];Pp[1]=Pc[1];Pp[2]=Pc[2]; }
        float T[9];
        rot6d(xb[j*6+0],xb[j*6+1],xb[j*6+2],xb[j*6+3],xb[j*6+4],xb[j*6+5],T);
        float o0=ob[j*3+0],o1=ob[j*3+1],o2=ob[j*3+2];
        Pc[0]=Rp[0]*o0+Rp[1]*o1+Rp[2]*o2+Pp[0];
        Pc[1]=Rp[3]*o0+Rp[4]*o1+Rp[5]*o2+Pp[1];
        Pc[2]=Rp[6]*o0+Rp[7]*o1+Rp[8]*o2+Pp[2];
        for (int i=0;i<3;++i) for (int k=0;k<3;++k) {
            float s=0.f; for (int m=0;m<3;++m) s+=Rp[i*3+m]*T[m*3+k];
            R[i*3+k]=s;
        }
        P[j*3+0]=Pc[0]; P[j*3+1]=Pc[1]; P[j*3+2]=Pc[2];
        if (j==11) { for (int i=0;i<9;++i) R11[i]=R[i]; P11[0]=Pc[0];P11[1]=Pc[1];P11[2]=Pc[2]; }
        if (j==12) { for (int i=0;i<9;++i) R12[i]=R[i]; P12[0]=Pc[0];P12[1]=Pc[1];P12[2]=Pc[2]; }
    }
}

extern "C" void kernel_launch(void* const* d_in, const int* in_sizes, int n_in,
                              void* d_out, int out_size, void* d_ws, size_t ws_size,
                              hipStream_t stream) {
    const float* x   = (const float*)d_in[0];
    const float* off = (const float*)d_in[2];
    float* out = (float*)d_out;
    int B = in_sizes[0] / 144;
    int nb = B / GPB;
    if (nb > 0)
        fk_kernel<<<nb, GPB, 0, stream>>>(x, off, out, B);
    int rem = B - nb * GPB;
    if (rem > 0)
        fk_tail<<<(rem + 255) / 256, 256, 0, stream>>>(x, off, out, nb * GPB, B);
}

// Round 5
// 21.560 us; speedup vs baseline: 1.1337x; 1.1337x over previous
//
#include <hip/hip_runtime.h>
#include <math.h>

// ForwardKinematics: B graphs x 24 joints, fixed tree (compile-time).
// 256-thread blocks (4 waves) own 64 graphs; lane t = graph-in-block.
// Wave->joint ownership:
//   w0: 0(root),1,2,3,4, 22,23    w1: 5,6,7,8
//   w2: 9,10,11,12,13 (publishes R11/P11/R12/P12)   w3: 14..21
// LDS arena (62.4 KB), alias-free by construction:
//   rows   0..143  XS  : x transposed [feature][graph], IMMUTABLE after sync0
//   rows 144..215  OS/OUTS: offsets; OUTS row 3J+c == OS row 3J+c (same joint),
//                  so overwrite is same-wave, program-ordered only
//   rows 216..239  HF  : exclusive handoff (R11:0-8 P11:9-11 R12:12-20 P12:21-23)
// R0 computed redundantly by w0/w1/w2 (removes a handoff + barrier).
// 3 uniform barriers total. 2 blocks/CU -> 2 waves/SIMD, 2 scheduling rounds.

#define PAD 65
#define G   64

#define XS(f,g)   arena[(f)*PAD + (g)]
#define OS(f,g)   arena[(144+(f))*PAD + (g)]
#define OUTS(r,g) arena[(144+(r))*PAD + (g)]
#define HF(r,g)   arena[(216+(r))*PAD + (g)]

__device__ __forceinline__ void rot6d(const float a[6], float T[9]) {
    float n1 = sqrtf(a[0]*a[0] + a[1]*a[1] + a[2]*a[2]) + 1e-12f;
    float i1 = 1.0f / n1;
    float b1x = a[0]*i1, b1y = a[1]*i1, b1z = a[2]*i1;
    float d = b1x*a[3] + b1y*a[4] + b1z*a[5];
    float ax = a[3] - d*b1x, ay = a[4] - d*b1y, az = a[5] - d*b1z;
    float n2 = sqrtf(ax*ax + ay*ay + az*az) + 1e-12f;
    float i2 = 1.0f / n2;
    float b2x = ax*i2, b2y = ay*i2, b2z = az*i2;
    T[0] = b1x; T[1] = b1y; T[2] = b1z;
    T[3] = b2x; T[4] = b2y; T[5] = b2z;
    T[6] = b1y*b2z - b1z*b2y;
    T[7] = b1z*b2x - b1x*b2z;
    T[8] = b1x*b2y - b1y*b2x;
}

// Pull joint J's rotation input (XS only) -> T.
template<int J>
__device__ __forceinline__ void pullX(const float* arena, int t, float T[9]) {
    float a[6];
#pragma unroll
    for (int c = 0; c < 6; ++c) a[c] = XS(6*J+c, t);
    rot6d(a, T);
}

// Pull joint J's rotation input + offset (owned wave only).
template<int J>
__device__ __forceinline__ void pull(const float* arena, int t, float T[9], float o[3]) {
    float a[6];
#pragma unroll
    for (int c = 0; c < 6; ++c) a[c] = XS(6*J+c, t);
#pragma unroll
    for (int c = 0; c < 3; ++c) o[c] = OS(3*J+c, t);
    rot6d(a, T);
}

// Chain step joint J: P' = R*o + P ; R' = R*T ; position -> OUTS row 3J.
template<int J>
__device__ __forceinline__ void chain_step(float* arena, int t, float R[9], float P[3],
                                           const float T[9], const float o[3]) {
    float p0 = R[0]*o[0] + R[1]*o[1] + R[2]*o[2] + P[0];
    float p1 = R[3]*o[0] + R[4]*o[1] + R[5]*o[2] + P[1];
    float p2 = R[6]*o[0] + R[7]*o[1] + R[8]*o[2] + P[2];
    float Rn[9];
#pragma unroll
    for (int i = 0; i < 3; ++i)
#pragma unroll
        for (int k = 0; k < 3; ++k)
            Rn[i*3+k] = R[i*3+0]*T[0+k] + R[i*3+1]*T[3+k] + R[i*3+2]*T[6+k];
#pragma unroll
    for (int i = 0; i < 9; ++i) R[i] = Rn[i];
    P[0] = p0; P[1] = p1; P[2] = p2;
    OUTS(3*J+0, t) = p0; OUTS(3*J+1, t) = p1; OUTS(3*J+2, t) = p2;
}

__global__ __launch_bounds__(256, 2) void fk_kernel(const float* __restrict__ x,
                                                    const float* __restrict__ off,
                                                    float* __restrict__ out) {
    __shared__ float arena[240 * PAD];   // 62400 B
    const int tid = threadIdx.x;
    const int w = tid >> 6;
    const int t = tid & 63;
    const long gb0 = (long)blockIdx.x * G;
    const float4* x4 = (const float4*)x;
    const float2* o2 = (const float2*)off;

    // ---- cooperative coalesced staging: x (64x36 float4) + off (64x36 float2) ----
    float4 xr[9]; float2 orr[9];
#pragma unroll
    for (int k = 0; k < 9; ++k) xr[k]  = x4[gb0*36 + k*256 + tid];
#pragma unroll
    for (int k = 0; k < 9; ++k) orr[k] = o2[gb0*36 + k*256 + tid];
#pragma unroll
    for (int k = 0; k < 9; ++k) {
        int i = k*256 + tid; int g = i/36, e = i - g*36;
        XS(4*e+0, g) = xr[k].x; XS(4*e+1, g) = xr[k].y;
        XS(4*e+2, g) = xr[k].z; XS(4*e+3, g) = xr[k].w;
    }
#pragma unroll
    for (int k = 0; k < 9; ++k) {
        int i = k*256 + tid; int g = i/36, e = i - g*36;
        OS(2*e+0, g) = orr[k].x; OS(2*e+1, g) = orr[k].y;
    }
    __syncthreads();                         // sync0: inputs staged; XS immutable from here

    float Ta[8][9], oa[8][3];                // per-wave T/offset slots (const-indexed)
    float R[9], P[3];

    // ---- phase 1: pulls + early chains (no cross-wave dependencies) ----
    if (w == 0) {
        pullX<0>(arena, t, R);               // R = R0
        pull<1>(arena, t, Ta[0], oa[0]);
        pull<2>(arena, t, Ta[1], oa[1]);
        pull<3>(arena, t, Ta[2], oa[2]);
        pull<4>(arena, t, Ta[3], oa[3]);
        pull<22>(arena, t, Ta[4], oa[4]);
        pull<23>(arena, t, Ta[5], oa[5]);
        P[0] = P[1] = P[2] = 0.0f;
        OUTS(0, t) = 0.0f; OUTS(1, t) = 0.0f; OUTS(2, t) = 0.0f;   // root position
        chain_step<1>(arena, t, R, P, Ta[0], oa[0]);
        chain_step<2>(arena, t, R, P, Ta[1], oa[1]);
        chain_step<3>(arena, t, R, P, Ta[2], oa[2]);
        chain_step<4>(arena, t, R, P, Ta[3], oa[3]);
    } else if (w == 1) {
        pullX<0>(arena, t, R);               // redundant R0
        pull<5>(arena, t, Ta[0], oa[0]);
        pull<6>(arena, t, Ta[1], oa[1]);
        pull<7>(arena, t, Ta[2], oa[2]);
        pull<8>(arena, t, Ta[3], oa[3]);
        P[0] = P[1] = P[2] = 0.0f;
        chain_step<5>(arena, t, R, P, Ta[0], oa[0]);
        chain_step<6>(arena, t, R, P, Ta[1], oa[1]);
        chain_step<7>(arena, t, R, P, Ta[2], oa[2]);
        chain_step<8>(arena, t, R, P, Ta[3], oa[3]);
    } else if (w == 2) {
        pullX<0>(arena, t, R);               // redundant R0
        pull<9> (arena, t, Ta[0], oa[0]);
        pull<10>(arena, t, Ta[1], oa[1]);
        pull<11>(arena, t, Ta[2], oa[2]);
        pull<12>(arena, t, Ta[3], oa[3]);
        pull<13>(arena, t, Ta[4], oa[4]);
        P[0] = P[1] = P[2] = 0.0f;
        chain_step<9> (arena, t, R, P, Ta[0], oa[0]);
        chain_step<10>(arena, t, R, P, Ta[1], oa[1]);
        chain_step<11>(arena, t, R, P, Ta[2], oa[2]);
#pragma unroll
        for (int i = 0; i < 9; ++i) HF(i, t) = R[i];        // R11
#pragma unroll
        for (int c = 0; c < 3; ++c) HF(9+c, t) = P[c];      // P11
        chain_step<12>(arena, t, R, P, Ta[3], oa[3]);
#pragma unroll
        for (int i = 0; i < 9; ++i) HF(12+i, t) = R[i];     // R12
#pragma unroll
        for (int c = 0; c < 3; ++c) HF(21+c, t) = P[c];     // P12
        chain_step<13>(arena, t, R, P, Ta[4], oa[4]);
    } else {
        pull<14>(arena, t, Ta[0], oa[0]);
        pull<15>(arena, t, Ta[1], oa[1]);
        pull<16>(arena, t, Ta[2], oa[2]);
        pull<17>(arena, t, Ta[3], oa[3]);
        pull<18>(arena, t, Ta[4], oa[4]);
        pull<19>(arena, t, Ta[5], oa[5]);
        pull<20>(arena, t, Ta[6], oa[6]);
        pull<21>(arena, t, Ta[7], oa[7]);
    }
    __syncthreads();                         // sync_a: R11/P11/R12/P12 published

    // ---- phase 2: consume handoffs ----
    if (w == 0) {                            // 22,23 from R12/P12
#pragma unroll
        for (int i = 0; i < 9; ++i) R[i] = HF(12+i, t);
#pragma unroll
        for (int c = 0; c < 3; ++c) P[c] = HF(21+c, t);
        chain_step<22>(arena, t, R, P, Ta[4], oa[4]);
        chain_step<23>(arena, t, R, P, Ta[5], oa[5]);
    } else if (w == 3) {                     // limbs from R11/P11
#pragma unroll
        for (int i = 0; i < 9; ++i) R[i] = HF(i, t);
#pragma unroll
        for (int c = 0; c < 3; ++c) P[c] = HF(9+c, t);
        chain_step<14>(arena, t, R, P, Ta[0], oa[0]);
        chain_step<15>(arena, t, R, P, Ta[1], oa[1]);
        chain_step<16>(arena, t, R, P, Ta[2], oa[2]);
        chain_step<17>(arena, t, R, P, Ta[3], oa[3]);
#pragma unroll
        for (int i = 0; i < 9; ++i) R[i] = HF(i, t);        // reload R11/P11 (exclusive region)
#pragma unroll
        for (int c = 0; c < 3; ++c) P[c] = HF(9+c, t);
        chain_step<18>(arena, t, R, P, Ta[4], oa[4]);
        chain_step<19>(arena, t, R, P, Ta[5], oa[5]);
        chain_step<20>(arena, t, R, P, Ta[6], oa[6]);
        chain_step<21>(arena, t, R, P, Ta[7], oa[7]);
    }
    __syncthreads();                         // sync_b: all 72 OUTS rows final

    // ---- coalesced flush: 64 graphs x 18 float4 = 1152 float4 ----
    float4* out4 = (float4*)out;
#pragma unroll
    for (int k = 0; k < 5; ++k) {
        int i = k*256 + tid;
        if (i < 1152) {
            int g = i/18, e = i - g*18;
            float4 v;
            v.x = OUTS(4*e+0, g); v.y = OUTS(4*e+1, g);
            v.z = OUTS(4*e+2, g); v.w = OUTS(4*e+3, g);
            out4[gb0*18 + i] = v;
        }
    }
}

// Fallback (per-thread whole graph) for B not divisible by 64 — not expected here.
__global__ __launch_bounds__(256) void fk_tail(const float* __restrict__ x,
                                               const float* __restrict__ off,
                                               float* __restrict__ out,
                                               int b0, int B) {
    int b = b0 + blockIdx.x * blockDim.x + threadIdx.x;
    if (b >= B) return;
    const float* xb = x + (size_t)b * 144;
    const float* ob = off + (size_t)b * 72;
    float* P = out + (size_t)b * 72;
    float R[9], Pc[3], R0[9], R11[9], P11[3], R12[9], P12[3];
    {
        float a[6] = {xb[0],xb[1],xb[2],xb[3],xb[4],xb[5]};
        rot6d(a, R);
        Pc[0] = Pc[1] = Pc[2] = 0.0f;
        P[0] = P[1] = P[2] = 0.0f;
        for (int i = 0; i < 9; ++i) R0[i] = R[i];
    }
    for (int j = 1; j < 24; ++j) {
        float Rp[9], Pp[3];
        if (j==1||j==5||j==9) { for (int i=0;i<9;++i) Rp[i]=R0[i]; Pp[0]=Pp[1]=Pp[2]=0.f; }
        else if (j==14||j==18) { for (int i=0;i<9;++i) Rp[i]=R11[i]; Pp[0]=P11[0];Pp[1]=P11[1];Pp[2]=P11[2]; }
        else if (j==22)   { for (int i=0;i<9;++i) Rp[i]=R12[i]; Pp[0]=P12[0];Pp[1]=P12[1];Pp[2]=P12[2]; }
        else              { for (int i=0;i<9;++i) Rp[i]=R[i];   Pp[0]=Pc[0];Pp[1]=Pc[1];Pp[2]=Pc[2]; }
        float T[9];
        float a[6] = {xb[j*6+0],xb[j*6+1],xb[j*6+2],xb[j*6+3],xb[j*6+4],xb[j*6+5]};
        rot6d(a, T);
        float o0=ob[j*3+0],o1=ob[j*3+1],o2=ob[j*3+2];
        Pc[0]=Rp[0]*o0+Rp[1]*o1+Rp[2]*o2+Pp[0];
        Pc[1]=Rp[3]*o0+Rp[4]*o1+Rp[5]*o2+Pp[1];
        Pc[2]=Rp[6]*o0+Rp[7]*o1+Rp[8]*o2+Pp[2];
        for (int i=0;i<3;++i) for (int k=0;k<3;++k) {
            float s=0.f; for (int m=0;m<3;++m) s+=Rp[i*3+m]*T[m*3+k];
            R[i*3+k]=s;
        }
        P[j*3+0]=Pc[0]; P[j*3+1]=Pc[1]; P[j*3+2]=Pc[2];
        if (j==11) { for (int i=0;i<9;++i) R11[i]=R[i]; P11[0]=Pc[0];P11[1]=Pc[1];P11[2]=Pc[2]; }
        if (j==12) { for (int i=0;i<9;++i) R12[i]=R[i]; P12[0]=Pc[0];P12[1]=Pc[1];P12[2]=Pc[2]; }
    }
}

extern "C" void kernel_launch(void* const* d_in, const int* in_sizes, int n_in,
                              void* d_out, int out_size, void* d_ws, size_t ws_size,
                              hipStream_t stream) {
    const float* x   = (const float*)d_in[0];
    const float* off = (const float*)d_in[2];
    float* out = (float*)d_out;
    int B = in_sizes[0] / 144;
    int nb = B / G;
    if (nb > 0)
        fk_kernel<<<nb, 256, 0, stream>>>(x, off, out);
    int rem = B - nb * G;
    if (rem > 0)
        fk_tail<<<(rem + 255) / 256, 256, 0, stream>>>(x, off, out, nb * G, B);
}